// Round 1
// baseline (106.175 us; speedup 1.0000x reference)
//
#include <hip/hip_runtime.h>

#define ALPHA 0.2f

constexpr int WDIM = 128;
constexpr int KDIM = 1024;

// per-batch workspace layout (float offsets)
constexpr int OFF_XT   = 0;        // [1024][128]  v = x^T
constexpr int OFF_A    = 131072;   // [1025][128]  prefix table (sorted desc by s2)
constexpr int OFF_B    = 262272;   // [1025][128]  suffix table
constexpr int OFF_ESC  = 393472;   // [1024] exp(s2 - M2) sorted
constexpr int OFF_ESCA = 394496;   // [1024] exp(alpha*s2) sorted
constexpr int OFF_AT   = 395520;   // [1025] scalar prefix
constexpr int OFF_BT   = 396545;   // [1025] scalar suffix
constexpr int OFF_U    = 397570;   // [1024]
constexpr int OFF_T    = 398594;   // [1024]
constexpr int OFF_S1   = 399618;   // [1024]
constexpr int OFF_S2   = 400642;   // [1024]
constexpr int OFF_CC   = 401666;   // [1024] int: c_i
constexpr int OFF_PERM = 402690;   // [1024] int: perm[rank] = j
constexpr int PBF      = 403840;   // per-batch stride (floats), 128-aligned

// K1: s1, s2, and transpose x -> xT (v). grid (8, nb) x 128
__global__ __launch_bounds__(128) void k_s12(const float* __restrict__ x,
                                             const float* __restrict__ w,
                                             float* __restrict__ ws, int b0) {
  const int slot = blockIdx.y;
  const int b = b0 + slot;
  float* base = ws + (size_t)slot * PBF;
  __shared__ float w1s[WDIM], w2s[WDIM];
  int t = threadIdx.x;
  if (t < WDIM) { w1s[t] = w[t]; w2s[t] = w[WDIM + t]; }
  __syncthreads();
  int j = blockIdx.x * 128 + t;
  const float* xb = x + (size_t)b * (WDIM * KDIM);
  float s1 = 0.f, s2 = 0.f;
  float* xrow = base + OFF_XT + j * WDIM;
  for (int w0 = 0; w0 < WDIM; w0 += 16) {
    float vals[16];
#pragma unroll
    for (int k2 = 0; k2 < 16; ++k2) {
      float v = xb[(w0 + k2) * KDIM + j];
      vals[k2] = v;
      s1 = fmaf(v, w1s[w0 + k2], s1);
      s2 = fmaf(v, w2s[w0 + k2], s2);
    }
#pragma unroll
    for (int q = 0; q < 4; ++q)
      *(float4*)(xrow + w0 + 4 * q) =
          make_float4(vals[4*q], vals[4*q+1], vals[4*q+2], vals[4*q+3]);
  }
  base[OFF_S1 + j] = s1;
  base[OFF_S2 + j] = s2;
}

// K2: rank (stable desc sort by counting), c_i, scatter esc/esca/perm, u/t.
// grid (8, nb) x 512 : jj = t>>2 covers 128 j's, quarter = t&3 splits compares
__global__ __launch_bounds__(512) void k_rank(float* __restrict__ ws) {
  const int slot = blockIdx.y;
  float* base = ws + (size_t)slot * PBF;
  __shared__ float s2s[KDIM];
  __shared__ float red[512];
  __shared__ int pr[128][4], pc[128][4];
  int t = threadIdx.x;
  for (int i = t; i < KDIM; i += 512) s2s[i] = base[OFF_S2 + i];
  __syncthreads();
  red[t] = fmaxf(s2s[t], s2s[t + 512]);
  __syncthreads();
  for (int s = 256; s > 0; s >>= 1) {
    if (t < s) red[t] = fmaxf(red[t], red[t + s]);
    __syncthreads();
  }
  float M2 = red[0];
  int jj = t >> 2, quarter = t & 3;
  int j = blockIdx.x * 128 + jj;
  float s2me = s2s[j];
  float s1me = base[OFF_S1 + j];
  float key = -s1me;
  int r = 0, c = 0;
  int lo = quarter * 256;
#pragma unroll 4
  for (int k2 = 0; k2 < 256; ++k2) {
    float v = s2s[lo + k2];
    int jp = lo + k2;
    r += (v > s2me || (v == s2me && jp < j)) ? 1 : 0;
    c += (v >= key) ? 1 : 0;
  }
  pr[jj][quarter] = r;
  pc[jj][quarter] = c;
  __syncthreads();
  if (quarter == 0) {
    int R = pr[jj][0] + pr[jj][1] + pr[jj][2] + pr[jj][3];
    int C = pc[jj][0] + pc[jj][1] + pc[jj][2] + pc[jj][3];
    ((int*)(base + OFF_CC))[j] = C;
    ((int*)(base + OFF_PERM))[R] = j;
    base[OFF_ESC + R] = __expf(s2me - M2);
    base[OFF_ESCA + R] = __expf(ALPHA * s2me);
    float z = s1me + M2;
    float mi = z >= 0.f ? z : ALPHA * z;
    base[OFF_U + j] = __expf(z - mi);          // exp(s1+M2-m) <= 1
    base[OFF_T + j] = __expf(ALPHA * s1me - mi);
  }
}

// K3: scalar prefix (a) / suffix (b) tables via Hillis-Steele. grid nb x 1024
__global__ __launch_bounds__(1024) void k_scan(float* __restrict__ ws) {
  float* base = ws + (size_t)blockIdx.x * PBF;
  __shared__ float sa[KDIM], sb[KDIM];
  int t = threadIdx.x;
  sa[t] = base[OFF_ESC + t];
  sb[t] = base[OFF_ESCA + t];
  __syncthreads();
  for (int s = 1; s < KDIM; s <<= 1) {
    float va = (t >= s) ? sa[t - s] : 0.f;
    float vb = (t + s < KDIM) ? sb[t + s] : 0.f;
    __syncthreads();
    sa[t] += va;
    sb[t] += vb;
    __syncthreads();
  }
  base[OFF_AT + t + 1] = sa[t];
  base[OFF_BT + t] = sb[t];
  if (t == 0) { base[OFF_AT] = 0.f; base[OFF_BT + KDIM] = 0.f; }
}

// K4: vector prefix/suffix tables A(c), B(c). 8 rank-segments x 128 w.
// Two passes: segment totals -> per-segment base, then store final rows.
__global__ __launch_bounds__(1024) void k_vtab(float* __restrict__ ws) {
  float* base = ws + (size_t)blockIdx.x * PBF;
  __shared__ float ea[KDIM], eb[KDIM];
  __shared__ int prm[KDIM];
  __shared__ float stA[8][WDIM], stB[8][WDIM];
  int t = threadIdx.x;
  ea[t] = base[OFF_ESC + t];
  eb[t] = base[OFF_ESCA + t];
  prm[t] = ((const int*)(base + OFF_PERM))[t];
  __syncthreads();
  int w = t & 127, seg = t >> 7;
  const float* xT = base + OFF_XT;
  int r0 = seg * 128;
  float ta = 0.f, tb = 0.f;
#pragma unroll 4
  for (int k2 = 0; k2 < 128; ++k2) {
    int r = r0 + k2;
    float xv = xT[prm[r] * WDIM + w];
    ta = fmaf(ea[r], xv, ta);
    tb = fmaf(eb[r], xv, tb);
  }
  stA[seg][w] = ta;
  stB[seg][w] = tb;
  __syncthreads();
  float baseA = 0.f, baseB = 0.f;
  for (int s = 0; s < seg; ++s) baseA += stA[s][w];
  for (int s = seg + 1; s < 8; ++s) baseB += stB[s][w];
  float* At = base + OFF_A;
  float* Bt = base + OFF_B;
  float acc = baseA;
#pragma unroll 4
  for (int k2 = 0; k2 < 128; ++k2) {
    int r = r0 + k2;
    At[r * WDIM + w] = acc;                       // A(c) = sum of ranks < c
    acc = fmaf(ea[r], xT[prm[r] * WDIM + w], acc);
  }
  if (seg == 7) At[KDIM * WDIM + w] = acc;
  acc = baseB;
#pragma unroll 4
  for (int k2 = 127; k2 >= 0; --k2) {
    int r = r0 + k2;
    acc = fmaf(eb[r], xT[prm[r] * WDIM + w], acc);
    Bt[r * WDIM + w] = acc;                       // B(c) = sum of ranks >= c
  }
  if (seg == 0) Bt[KDIM * WDIM + w] = 0.f;
}

// K5: h_i = (u*A(c_i) + t*B(c_i)) / (u*a(c_i) + t*b(c_i)). grid (128, nb) x 256
__global__ __launch_bounds__(256) void k_out(const float* __restrict__ ws,
                                             float* __restrict__ out, int b0) {
  const int slot = blockIdx.y;
  const int b = b0 + slot;
  const float* base = ws + (size_t)slot * PBF;
  int q = blockIdx.x * 256 + threadIdx.x;  // 0..32767
  int i = q >> 5;
  int wq = (q & 31) << 2;
  int c = ((const int*)(base + OFF_CC))[i];
  float u = base[OFF_U + i];
  float tt = base[OFF_T + i];
  float a = base[OFF_AT + c];
  float bb = base[OFF_BT + c];
  float rden = 1.f / fmaf(u, a, tt * bb);  // den >= 1 (argmax term)
  const float4 A4 = *(const float4*)(base + OFF_A + (size_t)c * WDIM + wq);
  const float4 B4 = *(const float4*)(base + OFF_B + (size_t)c * WDIM + wq);
  float4 o;
  o.x = (u * A4.x + tt * B4.x) * rden;
  o.y = (u * A4.y + tt * B4.y) * rden;
  o.z = (u * A4.z + tt * B4.z) * rden;
  o.w = (u * A4.w + tt * B4.w) * rden;
  *(float4*)(out + (size_t)b * (KDIM * WDIM) + (size_t)q * 4) = o;
}

extern "C" void kernel_launch(void* const* d_in, const int* in_sizes, int n_in,
                              void* d_out, int out_size, void* d_ws, size_t ws_size,
                              hipStream_t stream) {
  const float* x = (const float*)d_in[0];
  const float* w = (const float*)d_in[1];
  float* out = (float*)d_out;
  float* ws = (float*)d_ws;
  const int NB = 32;
  size_t perb = (size_t)PBF * sizeof(float);
  int nbmax = (int)(ws_size / perb);
  if (nbmax < 1) nbmax = 1;
  if (nbmax > NB) nbmax = NB;
  for (int b0 = 0; b0 < NB; b0 += nbmax) {
    int nb = (NB - b0 < nbmax) ? (NB - b0) : nbmax;
    k_s12<<<dim3(8, nb), 128, 0, stream>>>(x, w, ws, b0);
    k_rank<<<dim3(8, nb), 512, 0, stream>>>(ws);
    k_scan<<<nb, 1024, 0, stream>>>(ws);
    k_vtab<<<nb, 1024, 0, stream>>>(ws);
    k_out<<<dim3(128, nb), 256, 0, stream>>>(ws, out, b0);
  }
}

// Round 2
// 81.969 us; speedup vs baseline: 1.2953x; 1.2953x over previous
//
#include <hip/hip_runtime.h>

#define ALPHA 0.2f

constexpr int WDIM = 128;
constexpr int KDIM = 1024;
constexpr int NSEG = 32;             // rank segments for vtab
constexpr int SEGLEN = KDIM / NSEG;  // 32

// per-batch workspace layout (float offsets)
constexpr int OFF_XT   = 0;        // [1024][128]  v = x^T
constexpr int OFF_A    = 131072;   // [1025][128]  prefix table (sorted desc by s2)
constexpr int OFF_B    = 262272;   // [1025][128]  suffix table
constexpr int OFF_ESC  = 393472;   // [1024] exp(s2 - M2) sorted
constexpr int OFF_ESCA = 394496;   // [1024] exp(alpha*s2) sorted
constexpr int OFF_AT   = 395520;   // [1025] scalar prefix
constexpr int OFF_BT   = 396545;   // [1025] scalar suffix
constexpr int OFF_U    = 397570;   // [1024]
constexpr int OFF_T    = 398594;   // [1024]
constexpr int OFF_S1   = 399618;   // [1024]
constexpr int OFF_S2   = 400642;   // [1024]
constexpr int OFF_CC   = 401666;   // [1024] int: c_i
constexpr int OFF_PERM = 402690;   // [1024] int: perm[rank] = j
constexpr int OFF_TA   = 403840;   // [NSEG][128] segment totals (A side)
constexpr int OFF_TB   = 407936;   // [NSEG][128] segment totals (B side)
constexpr int PBF      = 412160;   // per-batch stride (floats), 128-aligned

// K1: s1, s2, and transpose x -> xT (v). grid (8, nb) x 128
__global__ __launch_bounds__(128) void k_s12(const float* __restrict__ x,
                                             const float* __restrict__ w,
                                             float* __restrict__ ws, int b0) {
  const int slot = blockIdx.y;
  const int b = b0 + slot;
  float* base = ws + (size_t)slot * PBF;
  __shared__ float w1s[WDIM], w2s[WDIM];
  int t = threadIdx.x;
  if (t < WDIM) { w1s[t] = w[t]; w2s[t] = w[WDIM + t]; }
  __syncthreads();
  int j = blockIdx.x * 128 + t;
  const float* xb = x + (size_t)b * (WDIM * KDIM);
  float s1 = 0.f, s2 = 0.f;
  float* xrow = base + OFF_XT + j * WDIM;
  for (int w0 = 0; w0 < WDIM; w0 += 16) {
    float vals[16];
#pragma unroll
    for (int k2 = 0; k2 < 16; ++k2) {
      float v = xb[(w0 + k2) * KDIM + j];
      vals[k2] = v;
      s1 = fmaf(v, w1s[w0 + k2], s1);
      s2 = fmaf(v, w2s[w0 + k2], s2);
    }
#pragma unroll
    for (int q = 0; q < 4; ++q)
      *(float4*)(xrow + w0 + 4 * q) =
          make_float4(vals[4*q], vals[4*q+1], vals[4*q+2], vals[4*q+3]);
  }
  base[OFF_S1 + j] = s1;
  base[OFF_S2 + j] = s2;
}

// K2: rank (stable desc sort by counting), c_i, scatter esc/esca/perm, u/t.
// grid (8, nb) x 512 : jj = t>>2 covers 128 j's, quarter = t&3 splits compares
__global__ __launch_bounds__(512) void k_rank(float* __restrict__ ws) {
  const int slot = blockIdx.y;
  float* base = ws + (size_t)slot * PBF;
  __shared__ float s2s[KDIM];
  __shared__ float red[512];
  __shared__ int pr[128][4], pc[128][4];
  int t = threadIdx.x;
  for (int i = t; i < KDIM; i += 512) s2s[i] = base[OFF_S2 + i];
  __syncthreads();
  red[t] = fmaxf(s2s[t], s2s[t + 512]);
  __syncthreads();
  for (int s = 256; s > 0; s >>= 1) {
    if (t < s) red[t] = fmaxf(red[t], red[t + s]);
    __syncthreads();
  }
  float M2 = red[0];
  int jj = t >> 2, quarter = t & 3;
  int j = blockIdx.x * 128 + jj;
  float s2me = s2s[j];
  float s1me = base[OFF_S1 + j];
  float key = -s1me;
  int r = 0, c = 0;
  int lo = quarter * 256;
#pragma unroll 4
  for (int k2 = 0; k2 < 256; ++k2) {
    float v = s2s[lo + k2];
    int jp = lo + k2;
    r += (v > s2me || (v == s2me && jp < j)) ? 1 : 0;
    c += (v >= key) ? 1 : 0;
  }
  pr[jj][quarter] = r;
  pc[jj][quarter] = c;
  __syncthreads();
  if (quarter == 0) {
    int R = pr[jj][0] + pr[jj][1] + pr[jj][2] + pr[jj][3];
    int C = pc[jj][0] + pc[jj][1] + pc[jj][2] + pc[jj][3];
    ((int*)(base + OFF_CC))[j] = C;
    ((int*)(base + OFF_PERM))[R] = j;
    base[OFF_ESC + R] = __expf(s2me - M2);
    base[OFF_ESCA + R] = __expf(ALPHA * s2me);
    float z = s1me + M2;
    float mi = z >= 0.f ? z : ALPHA * z;
    base[OFF_U + j] = __expf(z - mi);          // exp(s1+M2-m) <= 1
    base[OFF_T + j] = __expf(ALPHA * s1me - mi);
  }
}

// K3: scalar prefix (a) / suffix (b) tables via Hillis-Steele. grid nb x 1024
__global__ __launch_bounds__(1024) void k_scan(float* __restrict__ ws) {
  float* base = ws + (size_t)blockIdx.x * PBF;
  __shared__ float sa[KDIM], sb[KDIM];
  int t = threadIdx.x;
  sa[t] = base[OFF_ESC + t];
  sb[t] = base[OFF_ESCA + t];
  __syncthreads();
  for (int s = 1; s < KDIM; s <<= 1) {
    float va = (t >= s) ? sa[t - s] : 0.f;
    float vb = (t + s < KDIM) ? sb[t + s] : 0.f;
    __syncthreads();
    sa[t] += va;
    sb[t] += vb;
    __syncthreads();
  }
  base[OFF_AT + t + 1] = sa[t];
  base[OFF_BT + t] = sb[t];
  if (t == 0) { base[OFF_AT] = 0.f; base[OFF_BT + KDIM] = 0.f; }
}

// K4a: per-segment totals. grid (NSEG/2, nb) x 256 (two segments per block)
__global__ __launch_bounds__(256) void k_vtab_tot(float* __restrict__ ws) {
  const int slot = blockIdx.y;
  float* base = ws + (size_t)slot * PBF;
  int t = threadIdx.x;
  int w = t & 127, sl = t >> 7;
  int seg = blockIdx.x * 2 + sl;
  int r0 = seg * SEGLEN;
  const float* xT = base + OFF_XT;
  const int* prm = (const int*)(base + OFF_PERM);
  const float* ea = base + OFF_ESC;
  const float* eb = base + OFF_ESCA;
  float ta = 0.f, tb = 0.f;
#pragma unroll 4
  for (int k2 = 0; k2 < SEGLEN; ++k2) {
    int r = r0 + k2;
    float xv = xT[prm[r] * WDIM + w];
    ta = fmaf(ea[r], xv, ta);
    tb = fmaf(eb[r], xv, tb);
  }
  base[OFF_TA + seg * WDIM + w] = ta;
  base[OFF_TB + seg * WDIM + w] = tb;
}

// K4b: fused scan within each segment, bases from totals. grid (NSEG/2, nb) x 256
__global__ __launch_bounds__(256) void k_vtab_scan(float* __restrict__ ws) {
  const int slot = blockIdx.y;
  float* base = ws + (size_t)slot * PBF;
  int t = threadIdx.x;
  int w = t & 127, sl = t >> 7;
  int seg = blockIdx.x * 2 + sl;
  int r0 = seg * SEGLEN;
  const float* xT = base + OFF_XT;
  const int* prm = (const int*)(base + OFF_PERM);
  const float* ea = base + OFF_ESC;
  const float* eb = base + OFF_ESCA;
  float baseA = 0.f, baseB = 0.f;
  for (int s = 0; s < seg; ++s) baseA += base[OFF_TA + s * WDIM + w];
  for (int s = seg + 1; s < NSEG; ++s) baseB += base[OFF_TB + s * WDIM + w];
  float* At = base + OFF_A;
  float* Bt = base + OFF_B;
  float acc = baseA;
#pragma unroll 4
  for (int k2 = 0; k2 < SEGLEN; ++k2) {
    int r = r0 + k2;
    At[r * WDIM + w] = acc;                       // A(c) = sum of ranks < c
    acc = fmaf(ea[r], xT[prm[r] * WDIM + w], acc);
  }
  if (seg == NSEG - 1) At[KDIM * WDIM + w] = acc;
  acc = baseB;
#pragma unroll 4
  for (int k2 = SEGLEN - 1; k2 >= 0; --k2) {
    int r = r0 + k2;
    acc = fmaf(eb[r], xT[prm[r] * WDIM + w], acc);
    Bt[r * WDIM + w] = acc;                       // B(c) = sum of ranks >= c
  }
  if (seg == 0) Bt[KDIM * WDIM + w] = 0.f;
}

// K5: h_i = (u*A(c_i) + t*B(c_i)) / (u*a(c_i) + t*b(c_i)). grid (128, nb) x 256
__global__ __launch_bounds__(256) void k_out(const float* __restrict__ ws,
                                             float* __restrict__ out, int b0) {
  const int slot = blockIdx.y;
  const int b = b0 + slot;
  const float* base = ws + (size_t)slot * PBF;
  int q = blockIdx.x * 256 + threadIdx.x;  // 0..32767
  int i = q >> 5;
  int wq = (q & 31) << 2;
  int c = ((const int*)(base + OFF_CC))[i];
  float u = base[OFF_U + i];
  float tt = base[OFF_T + i];
  float a = base[OFF_AT + c];
  float bb = base[OFF_BT + c];
  float rden = 1.f / fmaf(u, a, tt * bb);  // den >= 1 (argmax term)
  const float4 A4 = *(const float4*)(base + OFF_A + (size_t)c * WDIM + wq);
  const float4 B4 = *(const float4*)(base + OFF_B + (size_t)c * WDIM + wq);
  float4 o;
  o.x = (u * A4.x + tt * B4.x) * rden;
  o.y = (u * A4.y + tt * B4.y) * rden;
  o.z = (u * A4.z + tt * B4.z) * rden;
  o.w = (u * A4.w + tt * B4.w) * rden;
  *(float4*)(out + (size_t)b * (KDIM * WDIM) + (size_t)q * 4) = o;
}

extern "C" void kernel_launch(void* const* d_in, const int* in_sizes, int n_in,
                              void* d_out, int out_size, void* d_ws, size_t ws_size,
                              hipStream_t stream) {
  const float* x = (const float*)d_in[0];
  const float* w = (const float*)d_in[1];
  float* out = (float*)d_out;
  float* ws = (float*)d_ws;
  const int NB = 32;
  size_t perb = (size_t)PBF * sizeof(float);
  int nbmax = (int)(ws_size / perb);
  if (nbmax < 1) nbmax = 1;
  if (nbmax > NB) nbmax = NB;
  for (int b0 = 0; b0 < NB; b0 += nbmax) {
    int nb = (NB - b0 < nbmax) ? (NB - b0) : nbmax;
    k_s12<<<dim3(8, nb), 128, 0, stream>>>(x, w, ws, b0);
    k_rank<<<dim3(8, nb), 512, 0, stream>>>(ws);
    k_scan<<<nb, 1024, 0, stream>>>(ws);
    k_vtab_tot<<<dim3(NSEG / 2, nb), 256, 0, stream>>>(ws);
    k_vtab_scan<<<dim3(NSEG / 2, nb), 256, 0, stream>>>(ws);
    k_out<<<dim3(128, nb), 256, 0, stream>>>(ws, out, b0);
  }
}